// Round 14
// baseline (1088.279 us; speedup 1.0000x reference)
//
#include <hip/hip_runtime.h>

// RegressorHybrid: per-edge 2x MLP (128->64->64->32->1, lrelu 0.01), E=2M, H=64.
// Round 20: request the 3-wave tier AND make it comfortable.
// R19 (all weights LDS, 181us): occupancy STUCK at 21.5% - VGPR_Count=120 is
// arch-only; HW tier = arch+AGPR unified. With launch_bounds(256,2) the
// compiler parks accumulators (accP/accN/acc2 ~48-56) in AGPRs up to the 256
// budget -> ~176 > 170 (3-wave boundary). The allocator never voluntarily
// comes in under a tier; the tier must be REQUESTED (launch_bounds(256,3),
// budget 170) - but R7/R8 proved a request within spill-chasing distance of
// demand is fatal. So: also DROP the skew pipeline (R18) - its job (fill
// dependency gaps with ILP at 2 waves) is done by TLP at 3 waves, and
// dropping accN's double-residency moves demand to ~130-150: a real 20-40
// reg margin under 170. Serial layer order = R16's, with in-place gather.
// Kept: all weights+biases in LDS (38912 B -> 4 blocks/CU, not binding:
// R10 -11% at 40->16 reads, R17 null at 16->8), w4 in regs, warm depth 3
// (W0-W2), eidx I1-I3 rotating prefetch, setprio(1) compute / 0 memory,
// packed cvt_pkrtz repack, stride-8 pairing (m=(bid>>3)&1) for L2 warm
// dedup, warm law R1-R5 (one warm b128 covers the tile's 64 lines; consume
// gathers hit L1/L2; FETCH 185MB = raw).
// MFMA layouts: A[m=lane&15][k=(lane>>4)*8+j], B[k=(lane>>4)*8+j][n=lane&15],
//               C/D[row=4*(lane>>4)+reg][col=lane&15].

typedef _Float16 half8  __attribute__((ext_vector_type(8)));
typedef _Float16 half4v __attribute__((ext_vector_type(4)));
typedef _Float16 half2v __attribute__((ext_vector_type(2)));
typedef float    float4v __attribute__((ext_vector_type(4)));

#define MLP_W_BYTES 28672          // w1f 16384 + w2f 8192 + w3f 4096
#define MLP_R_BYTES 12288          // w4f 2048 + b1f 4096 + b2f 4096 + b3f 2048
#define W1F 0
#define W2F 16384
#define W3F 24576
#define LB1F 28672                 // LDS offsets for biases
#define LB2F 32768
#define LB3F 36864
#define LDS_TOTAL 38912            // w1f+w2f+w3f 28672 + b1f 4096 + b2f 4096 + b3f 2048
#define WS_REST_OFF 57344
#define WS_X16_OFF  81920

__device__ __forceinline__ float lrelu(float x) { return fmaxf(x, 0.01f * x); }

__device__ __forceinline__ int uperm(int k) {
    return 16 * (2 * ((k >> 2) & 1) + ((k >> 5) & 1)) + 4 * ((k >> 3) & 3) + (k & 3);
}

// ---- pack one MLP's weights/biases into per-lane fragment order ----
__global__ void prep_frags(const float* __restrict__ w1, const float* __restrict__ b1,
                           const float* __restrict__ w2, const float* __restrict__ b2,
                           const float* __restrict__ w3, const float* __restrict__ b3,
                           const float* __restrict__ w4,
                           unsigned char* __restrict__ dstL,
                           unsigned char* __restrict__ dstR)
{
    int idx = blockIdx.x * blockDim.x + threadIdx.x;
    if (idx < 8192) {                      // w1f: [16 frags][64 lanes][8 f16]
        int L = (idx >> 3) & 63, j = idx & 7, f = idx >> 9;
        int q = L >> 4, mm = L & 15, t = f >> 2, s = f & 3;
        int k = 32 * s + 8 * q + j;
        ((_Float16*)(dstL + W1F))[idx] = (_Float16)w1[k * 64 + 16 * t + mm];
        return;
    }
    idx -= 8192;
    if (idx < 4096) {                      // w2f: [8][64][8]
        int L = (idx >> 3) & 63, j = idx & 7, f = idx >> 9;
        int q = L >> 4, mm = L & 15, t = f >> 1, s = f & 1;
        int u = uperm(32 * s + 8 * q + j);
        ((_Float16*)(dstL + W2F))[idx] = (_Float16)w2[u * 64 + 16 * t + mm];
        return;
    }
    idx -= 4096;
    if (idx < 2048) {                      // w3f: [4][64][8]
        int L = (idx >> 3) & 63, j = idx & 7, f = idx >> 9;
        int q = L >> 4, mm = L & 15, t = f >> 1, s = f & 1;
        int u = uperm(32 * s + 8 * q + j);
        ((_Float16*)(dstL + W3F))[idx] = (_Float16)w3[u * 32 + 16 * t + mm];
        return;
    }
    idx -= 2048;
    if (idx < 512) {                       // w4f
        int L = idx >> 3, j = idx & 7;
        int q = L >> 4, t = j >> 2, r = j & 3;
        ((float*)(dstR + 0))[idx] = w4[16 * t + 4 * q + r];
        return;
    }
    idx -= 512;
    if (idx < 1024) {                      // b1f
        int t = idx >> 8, L = (idx >> 2) & 63, r = idx & 3, q = L >> 4;
        ((float*)(dstR + 2048))[idx] = b1[16 * t + 4 * q + r];
        return;
    }
    idx -= 1024;
    if (idx < 1024) {                      // b2f
        int t = idx >> 8, L = (idx >> 2) & 63, r = idx & 3, q = L >> 4;
        ((float*)(dstR + 6144))[idx] = b2[16 * t + 4 * q + r];
        return;
    }
    idx -= 1024;
    if (idx < 512) {                       // b3f
        int t = idx >> 8, L = (idx >> 2) & 63, r = idx & 3, q = L >> 4;
        ((float*)(dstR + 10240))[idx] = b3[16 * t + 4 * q + r];
        return;
    }
}

// ---- convert node tables fp32 -> f16 ----
__global__ void prep_nodes(const float* __restrict__ xs, const float* __restrict__ xd,
                           _Float16* __restrict__ os, _Float16* __restrict__ od, int n4)
{
    int stride = gridDim.x * blockDim.x;
    for (int i = blockIdx.x * blockDim.x + threadIdx.x; i < n4; i += stride) {
        float4v a = ((const float4v*)xs)[i];
        float4v b = ((const float4v*)xd)[i];
        half4v ha, hb;
#pragma unroll
        for (int j = 0; j < 4; ++j) { ha[j] = (_Float16)a[j]; hb[j] = (_Float16)b[j]; }
        ((half4v*)os)[i] = ha;
        ((half4v*)od)[i] = hb;
    }
}

// packed repack: cvt_pkrtz (2 f32 -> 2 f16) then lrelu in f16 (pk mul+max).
__device__ __forceinline__ half2v cvt_pk(float a, float b) {
    return __builtin_bit_cast(half2v, __builtin_amdgcn_cvt_pkrtz(a, b));
}

__device__ __forceinline__ half8 repack2(float4v lo, float4v hi) {
    half8 r;
#pragma unroll
    for (int j = 0; j < 2; ++j) {
        half2v a = cvt_pk(lo[2 * j], lo[2 * j + 1]);
        half2v sa = a * (_Float16)0.01f;
        half2v ma = __builtin_elementwise_max(a, sa);
        r[2 * j] = ma[0]; r[2 * j + 1] = ma[1];
        half2v b = cvt_pk(hi[2 * j], hi[2 * j + 1]);
        half2v sb = b * (_Float16)0.01f;
        half2v mb = __builtin_elementwise_max(b, sb);
        r[4 + 2 * j] = mb[0]; r[4 + 2 * j + 1] = mb[1];
    }
    return r;
}

// eidx prefetch: (src,dst) node index pair for this lane's edge of a tile
__device__ __forceinline__ int2 load_eidx(const int* __restrict__ eidx,
                                          int nE, int tile, int n)
{
    int e = tile * 16 + n;
    int ec = e < nE ? e : nE - 1;
    return make_int2(eidx[ec], eidx[nE + ec]);
}

// R2-style consume gather from prefetched indices: lane (q,n) loads chunk q
// of edge n's 4 lines. Requests HIT L1/L2 (warmed iterations earlier).
__device__ __forceinline__ void gather_tile(const _Float16* __restrict__ xs,
                                            const _Float16* __restrict__ xd,
                                            int2 sd, int q, int4* G)
{
    const char* rs = (const char*)(xs + (size_t)sd.x * 64);
    const char* rd = (const char*)(xd + (size_t)sd.y * 64);
    G[0] = *(const int4*)(rs + 16 * q);
    G[1] = *(const int4*)(rs + 64 + 16 * q);
    G[2] = *(const int4*)(rd + 16 * q);
    G[3] = *(const int4*)(rd + 64 + 16 * q);
}

// warm pass from prefetched indices: lane (c=q, n) touches line (edge n,
// combo c) once -> 64 distinct lines per instruction, one 64B fill each.
__device__ __forceinline__ int4 warm_tile(const _Float16* __restrict__ xs,
                                          const _Float16* __restrict__ xd,
                                          int2 sd, int c)
{
    int idx = (c & 2) ? sd.y : sd.x;
    const char* base = (const char*)(((c & 2) ? xd : xs) + (size_t)idx * 64);
    return *(const int4*)(base + (c & 1) * 64);
}

__global__ __launch_bounds__(256, 3)
void edge_mlp_mfma(const unsigned char* __restrict__ ws,
                   const _Float16* __restrict__ xs, const _Float16* __restrict__ xd,
                   const int* __restrict__ eidx,
                   const float* __restrict__ eb4p, const float* __restrict__ wb4p,
                   float* __restrict__ out, int nE, int ntiles)
{
    __shared__ unsigned char lds[LDS_TOTAL];
    // stride-8 pairing: blocks 16k+j and 16k+8+j (j<8) run the same tiles for
    // m=0/1 -> same XCD (%8 preserved) and adjacent dispatch -> L2 dedup.
    const int m = (blockIdx.x >> 3) & 1;
    const int bid = (blockIdx.x & 7) | ((blockIdx.x >> 4) << 3);
    const unsigned char* wbase = ws + m * MLP_W_BYTES;
    const unsigned char* rbase = ws + WS_REST_OFF + m * MLP_R_BYTES;
    {
        const uint4* s = (const uint4*)(wbase + W1F);      // w1f|w2f|w3f contiguous
        uint4* d = (uint4*)lds;
        for (int i = threadIdx.x; i < 1792; i += 256) d[i] = s[i];
        const uint4* sb = (const uint4*)(rbase + 2048);     // b1f|b2f|b3f contiguous
        uint4* db = (uint4*)(lds + LB1F);
        for (int i = threadIdx.x; i < 640; i += 256) db[i] = sb[i];
    }

    const int lane = threadIdx.x & 63;
    const int q = lane >> 4, n = lane & 15;
    const int wid = (bid << 2) | (threadIdx.x >> 6);
    const int nwaves = gridDim.x << 1;     // (grid/2 blocks per MLP) * 4 waves
    const float b4s = m ? wb4p[0] : eb4p[0];
    float* __restrict__ outm = out + (m ? nE : 0);

    // ---- only w4 stays in registers (8) ----
    float4v w40 = *(const float4v*)(rbase + 0 + lane * 32);
    float4v w41 = *(const float4v*)(rbase + 0 + lane * 32 + 16);

    __syncthreads();

    int4 Gcur[4];
    int4 W0 = {0,0,0,0}, W1 = {0,0,0,0}, W2 = {0,0,0,0}, junk = {0,0,0,0};
    int2 I1 = {0,0}, I2 = {0,0}, I3 = {0,0};

    int tile = wid;
    if (tile < ntiles) {
        int t1 = tile + nwaves;     if (t1 >= ntiles) t1 = ntiles - 1;
        int t2 = tile + 2 * nwaves; if (t2 >= ntiles) t2 = ntiles - 1;
        int t3 = tile + 3 * nwaves; if (t3 >= ntiles) t3 = ntiles - 1;
        int2 I0 = load_eidx(eidx, nE, tile, n);
        I1 = load_eidx(eidx, nE, t1, n);
        I2 = load_eidx(eidx, nE, t2, n);
        I3 = load_eidx(eidx, nE, t3, n);
        W0 = warm_tile(xs, xd, I0, q);
        W1 = warm_tile(xs, xd, I1, q);
        W2 = warm_tile(xs, xd, I2, q);
        gather_tile(xs, xd, I0, q, Gcur);
    }

#pragma unroll 1
    for (; tile < ntiles; tile += nwaves) {
        half8 B1[4];
#pragma unroll
        for (int s = 0; s < 4; ++s) B1[s] = __builtin_bit_cast(half8, Gcur[s]);

        // ---- layer 1: 128 -> 64 (bias C-init from LDS, A from LDS) ----
        __builtin_amdgcn_s_setprio(1);
        float4v acc[4];
#pragma unroll
        for (int t = 0; t < 4; ++t) {
            acc[t] = *(const float4v*)(lds + LB1F + (t * 64 + lane) * 16);
#pragma unroll
            for (int s = 0; s < 4; ++s) {
                half8 A = *(const half8*)(lds + W1F + ((t * 4 + s) * 64 + lane) * 16);
                acc[t] = __builtin_amdgcn_mfma_f32_16x16x32_f16(A, B1[s], acc[t], 0, 0, 0);
            }
        }
        __builtin_amdgcn_s_setprio(0);

        // memory-issue block (low prio: let other waves' compute run):
        // Gcur dead (B1 consumed) -> gather NEXT tile into it in place.
        // Lines warmed 3 iterations ago -> L1/L2 hits; result consumed at
        // next loop top -> covered by layers 2-4 (~2K cyc >> 120cy).
        gather_tile(xs, xd, I1, q, Gcur);

        // fold oldest warm (3 iters old -> complete), rotate, issue new warm
        junk.x ^= W0.x; junk.y ^= W0.y; junk.z ^= W0.z; junk.w ^= W0.w;
        W0 = W1; W1 = W2;
        W2 = warm_tile(xs, xd, I3, q);

        // rotate eidx pipeline; issue fetch for tile+4nw
        {
            int t4 = tile + 4 * nwaves; if (t4 >= ntiles) t4 = ntiles - 1;
            I1 = I2; I2 = I3;
            I3 = load_eidx(eidx, nE, t4, n);
        }

        // ---- layers 2-4 (A from LDS; high prio) ----
        __builtin_amdgcn_s_setprio(1);
        half8 B2[2] = { repack2(acc[0], acc[2]), repack2(acc[1], acc[3]) };
        float4v acc2[4];
#pragma unroll
        for (int t = 0; t < 4; ++t) {
            acc2[t] = *(const float4v*)(lds + LB2F + (t * 64 + lane) * 16);
#pragma unroll
            for (int s = 0; s < 2; ++s) {
                half8 A = *(const half8*)(lds + W2F + ((t * 2 + s) * 64 + lane) * 16);
                acc2[t] = __builtin_amdgcn_mfma_f32_16x16x32_f16(A, B2[s], acc2[t], 0, 0, 0);
            }
        }
        half8 B3[2] = { repack2(acc2[0], acc2[2]), repack2(acc2[1], acc2[3]) };
        float4v acc3[2];
#pragma unroll
        for (int t = 0; t < 2; ++t) {
            acc3[t] = *(const float4v*)(lds + LB3F + (t * 64 + lane) * 16);
#pragma unroll
            for (int s = 0; s < 2; ++s) {
                half8 A = *(const half8*)(lds + W3F + ((t * 2 + s) * 64 + lane) * 16);
                acc3[t] = __builtin_amdgcn_mfma_f32_16x16x32_f16(A, B3[s], acc3[t], 0, 0, 0);
            }
        }
        float o = 0.f;
#pragma unroll
        for (int r = 0; r < 4; ++r) o = fmaf(lrelu(acc3[0][r]), w40[r], o);
#pragma unroll
        for (int r = 0; r < 4; ++r) o = fmaf(lrelu(acc3[1][r]), w41[r], o);
        o += __shfl_xor(o, 16, 64);
        o += __shfl_xor(o, 32, 64);
        __builtin_amdgcn_s_setprio(0);

        int e = tile * 16 + n;
        if (q == 0 && e < nE)
            outm[e] = o + b4s;
    }

    // consume warm registers (never-taken, data-dependent guard defeats DCE)
    junk.x ^= W0.x ^ W1.x ^ W2.x;
    junk.y ^= W0.y ^ W1.y ^ W2.y;
    junk.z ^= W0.z ^ W1.z ^ W2.z;
    junk.w ^= W0.w ^ W1.w ^ W2.w;
    if (nE < 0 && (junk.x | junk.y | junk.z | junk.w) != 0)
        out[0] = -1.0f;
}

extern "C" void kernel_launch(void* const* d_in, const int* in_sizes, int n_in,
                              void* d_out, int out_size, void* d_ws, size_t ws_size,
                              hipStream_t stream)
{
    const float* x_src = (const float*)d_in[0];
    const float* x_dst = (const float*)d_in[1];
    const int*   eidx  = (const int*)d_in[2];
    const float* ew1 = (const float*)d_in[3];
    const float* eb1 = (const float*)d_in[4];
    const float* ww1 = (const float*)d_in[5];
    const float* wb1 = (const float*)d_in[6];
    const float* ew2 = (const float*)d_in[7];
    const float* eb2 = (const float*)d_in[8];
    const float* ww2 = (const float*)d_in[9];
    const float* wb2 = (const float*)d_in[10];
    const float* ew3 = (const float*)d_in[11];
    const float* eb3 = (const float*)d_in[12];
    const float* ww3 = (const float*)d_in[13];
    const float* wb3 = (const float*)d_in[14];
    const float* ew4 = (const float*)d_in[15];
    const float* eb4 = (const float*)d_in[16];
    const float* ww4 = (const float*)d_in[17];
    const float* wb4 = (const float*)d_in[18];
    float* out = (float*)d_out;

    const int nE = in_sizes[2] / 2;          // 2 x E index array (int32)
    const int nNodeElems = in_sizes[0];      // N_NODES * 64
    unsigned char* ws = (unsigned char*)d_ws;
    _Float16* xs16 = (_Float16*)(ws + WS_X16_OFF);
    _Float16* xd16 = xs16 + nNodeElems;

    prep_frags<<<68, 256, 0, stream>>>(ew1, eb1, ew2, eb2, ew3, eb3, ew4,
                                       ws, ws + WS_REST_OFF);
    prep_frags<<<68, 256, 0, stream>>>(ww1, wb1, ww2, wb2, ww3, wb3, ww4,
                                       ws + MLP_W_BYTES, ws + WS_REST_OFF + MLP_R_BYTES);
    prep_nodes<<<1024, 256, 0, stream>>>(x_src, x_dst, xs16, xd16, nNodeElems / 4);

    const int ntiles = (nE + 15) / 16;
    edge_mlp_mfma<<<1024, 256, 0, stream>>>(ws, xs16, xd16, eidx, eb4, wb4,
                                            out, nE, ntiles);
}

// Round 15
// 399.087 us; speedup vs baseline: 2.7269x; 2.7269x over previous
//
#include <hip/hip_runtime.h>

// RegressorHybrid: per-edge 2x MLP (128->64->64->32->1, lrelu 0.01), E=2M, H=64.
// Round 21: algebraic restructure - precompute layer 1 per NODE.
// R20 ((256,3) request) spill-chased AGAIN (VGPR 84, WRITE 86MB, 990us):
// 3rd proof that any occupancy request near demand is fatal; 2 waves/SIMD
// is this kernel's operating point. So attack the WORK: layer 1 is 57% of
// MACs (8192/14368) and 16/28 MFMAs per edge, but it's linear in the
// gathered features: lrelu(src@Wtop + dst@Wbot + b1). Precompute per node
// (50K nodes vs 2M edges = 40x less work): h1_src = x_src@Wtop + b1,
// h1_dst = x_dst@Wbot, stored f16 natural order (4 tables: srcE,dstE,
// srcW,dstW; 25.6MB in ws, L3-resident). Per edge: gather h1 rows (128B/
// side - same bytes as x gather), 8 pk_add + lrelu, feed layer 2 directly:
// lane (q,n) needs features 16t+4q+r = int2 @ byte 32t+8q; B2[0]=[t0,t2],
// B2[1]=[t1,t3] = exactly repack2's output, so uperm'd w2f unchanged.
// Per tile: MFMA 28->12, LDS b128 38->18, layer-1 chain deleted, regs
// shrink (Gs/Gd 8 int2; acc/B1 gone). Warm law (R1-R5) transfers: h1 row
// = 2 lines/side, one warm b128 covers the tile's 64 lines.
// Kept: serial layer order + in-place gather (Gs/Gd dead after sums),
// warm depth 3, eidx I1-I3 prefetch, setprio, stride-8 pairing,
// launch_bounds(256,2) (NO occupancy request - R7/R8/R20 law).
// MFMA layouts: A[m=lane&15][k=(lane>>4)*8+j], B[k=(lane>>4)*8+j][n=lane&15],
//               C/D[row=4*(lane>>4)+reg][col=lane&15].

typedef _Float16 half8  __attribute__((ext_vector_type(8)));
typedef _Float16 half4v __attribute__((ext_vector_type(4)));
typedef _Float16 half2v __attribute__((ext_vector_type(2)));
typedef float    float4v __attribute__((ext_vector_type(4)));

#define MLP_W_BYTES 28672          // w1f 16384 + w2f 8192 + w3f 4096
#define MLP_R_BYTES 12288          // w4f 2048 + b1f 4096 + b2f 4096 + b3f 2048
#define W1F 0
#define W2F 16384
#define W3F 24576
#define LW2F 0                     // LDS: w2f 8192
#define LW3F 8192                  //      w3f 4096
#define LB2F 12288                 //      b2f 4096
#define LB3F 16384                 //      b3f 2048
#define LDS_TOTAL 18432
#define WS_REST_OFF 57344
#define WS_H1_OFF   81920          // 4 tables x nNodes x 128B

__device__ __forceinline__ float lrelu(float x) { return fmaxf(x, 0.01f * x); }

__device__ __forceinline__ int uperm(int k) {
    return 16 * (2 * ((k >> 2) & 1) + ((k >> 5) & 1)) + 4 * ((k >> 3) & 3) + (k & 3);
}

// ---- pack one MLP's weights/biases into per-lane fragment order ----
__global__ void prep_frags(const float* __restrict__ w1, const float* __restrict__ b1,
                           const float* __restrict__ w2, const float* __restrict__ b2,
                           const float* __restrict__ w3, const float* __restrict__ b3,
                           const float* __restrict__ w4,
                           unsigned char* __restrict__ dstL,
                           unsigned char* __restrict__ dstR)
{
    int idx = blockIdx.x * blockDim.x + threadIdx.x;
    if (idx < 8192) {                      // w1f: [16 frags][64 lanes][8 f16]
        int L = (idx >> 3) & 63, j = idx & 7, f = idx >> 9;
        int q = L >> 4, mm = L & 15, t = f >> 2, s = f & 3;
        int k = 32 * s + 8 * q + j;
        ((_Float16*)(dstL + W1F))[idx] = (_Float16)w1[k * 64 + 16 * t + mm];
        return;
    }
    idx -= 8192;
    if (idx < 4096) {                      // w2f: [8][64][8]
        int L = (idx >> 3) & 63, j = idx & 7, f = idx >> 9;
        int q = L >> 4, mm = L & 15, t = f >> 1, s = f & 1;
        int u = uperm(32 * s + 8 * q + j);
        ((_Float16*)(dstL + W2F))[idx] = (_Float16)w2[u * 64 + 16 * t + mm];
        return;
    }
    idx -= 4096;
    if (idx < 2048) {                      // w3f: [4][64][8]
        int L = (idx >> 3) & 63, j = idx & 7, f = idx >> 9;
        int q = L >> 4, mm = L & 15, t = f >> 1, s = f & 1;
        int u = uperm(32 * s + 8 * q + j);
        ((_Float16*)(dstL + W3F))[idx] = (_Float16)w3[u * 32 + 16 * t + mm];
        return;
    }
    idx -= 2048;
    if (idx < 512) {                       // w4f
        int L = idx >> 3, j = idx & 7;
        int q = L >> 4, t = j >> 2, r = j & 3;
        ((float*)(dstR + 0))[idx] = w4[16 * t + 4 * q + r];
        return;
    }
    idx -= 512;
    if (idx < 1024) {                      // b1f
        int t = idx >> 8, L = (idx >> 2) & 63, r = idx & 3, q = L >> 4;
        ((float*)(dstR + 2048))[idx] = b1[16 * t + 4 * q + r];
        return;
    }
    idx -= 1024;
    if (idx < 1024) {                      // b2f
        int t = idx >> 8, L = (idx >> 2) & 63, r = idx & 3, q = L >> 4;
        ((float*)(dstR + 6144))[idx] = b2[16 * t + 4 * q + r];
        return;
    }
    idx -= 1024;
    if (idx < 512) {                       // b3f
        int t = idx >> 8, L = (idx >> 2) & 63, r = idx & 3, q = L >> 4;
        ((float*)(dstR + 10240))[idx] = b3[16 * t + 4 * q + r];
        return;
    }
}

// ---- per-node layer-1 precompute: h1 tables (4 x nNodes x 64 f16) ----
// wave v of each block: m = v>>1 (MLP), side = v&1 (0: src@Wtop+b1, 1: dst@Wbot)
// 16 nodes per block; fp32 x read directly, f16 (RTN) store.
__global__ void h1_build(const unsigned char* __restrict__ ws,
                         const float* __restrict__ xs, const float* __restrict__ xd,
                         _Float16* __restrict__ h1, int nNodes)
{
    const int lane = threadIdx.x & 63;
    const int v = threadIdx.x >> 6;
    const int q = lane >> 4, n = lane & 15;
    const int m = v >> 1, side = v & 1;
    const unsigned char* wbase = ws + m * MLP_W_BYTES;
    const unsigned char* rbase = ws + WS_REST_OFF + m * MLP_R_BYTES;
    int node = blockIdx.x * 16 + n;
    int nc = node < nNodes ? node : nNodes - 1;
    const float* xrow = (side ? xd : xs) + (size_t)nc * 64;

    half8 B[2];
#pragma unroll
    for (int sl = 0; sl < 2; ++sl) {
        float4v lo = *(const float4v*)((const char*)xrow + 128 * sl + 32 * q);
        float4v hi = *(const float4v*)((const char*)xrow + 128 * sl + 32 * q + 16);
        half8 b;
#pragma unroll
        for (int j = 0; j < 4; ++j) { b[j] = (_Float16)lo[j]; b[4 + j] = (_Float16)hi[j]; }
        B[sl] = b;
    }
    float4v acc[4];
#pragma unroll
    for (int t = 0; t < 4; ++t) {
        if (side == 0) acc[t] = *(const float4v*)(rbase + 2048 + (t * 64 + lane) * 16);
        else           acc[t] = (float4v){0.f, 0.f, 0.f, 0.f};
#pragma unroll
        for (int sl = 0; sl < 2; ++sl) {
            int s = 2 * side + sl;
            half8 A = *(const half8*)(wbase + W1F + ((t * 4 + s) * 64 + lane) * 16);
            acc[t] = __builtin_amdgcn_mfma_f32_16x16x32_f16(A, B[sl], acc[t], 0, 0, 0);
        }
    }
    _Float16* orow = h1 + ((size_t)(m * 2 + side) * nNodes + nc) * 64;
#pragma unroll
    for (int t = 0; t < 4; ++t) {
        half4v hv;
#pragma unroll
        for (int r = 0; r < 4; ++r) hv[r] = (_Float16)acc[t][r];     // RTN
        *(half4v*)((char*)orow + 32 * t + 8 * q) = hv;
    }
}

// eidx prefetch: (src,dst) node index pair for this lane's edge of a tile
__device__ __forceinline__ int2 load_eidx(const int* __restrict__ eidx,
                                          int nE, int tile, int n)
{
    int e = tile * 16 + n;
    int ec = e < nE ? e : nE - 1;
    return make_int2(eidx[ec], eidx[nE + ec]);
}

// consume gather: lane (q,n) loads its 4 int2 per side (features 16t+4q+r
// at byte 32t+8q of the 128B h1 row). Hits L1/L2 (warmed earlier).
__device__ __forceinline__ void gather_h1(const _Float16* __restrict__ hs,
                                          const _Float16* __restrict__ hd,
                                          int2 sd, int q, int2* Gs, int2* Gd)
{
    const char* rs = (const char*)(hs + (size_t)sd.x * 64);
    const char* rd = (const char*)(hd + (size_t)sd.y * 64);
#pragma unroll
    for (int t = 0; t < 4; ++t) {
        Gs[t] = *(const int2*)(rs + 32 * t + 8 * q);
        Gd[t] = *(const int2*)(rd + 32 * t + 8 * q);
    }
}

// warm pass: lane (c=q, n) touches line (edge n, combo c) once -> 64
// distinct lines per instruction, one 64B fill each (R1-R5 law).
__device__ __forceinline__ int4 warm_h1(const _Float16* __restrict__ hs,
                                        const _Float16* __restrict__ hd,
                                        int2 sd, int c)
{
    const _Float16* tb = (c & 2) ? hd : hs;
    int idx = (c & 2) ? sd.y : sd.x;
    return *(const int4*)((const char*)(tb + (size_t)idx * 64) + (c & 1) * 64);
}

__global__ __launch_bounds__(256, 2)
void edge_mlp_mfma(const unsigned char* __restrict__ ws,
                   const _Float16* __restrict__ h1,
                   const int* __restrict__ eidx,
                   const float* __restrict__ eb4p, const float* __restrict__ wb4p,
                   float* __restrict__ out, int nE, int ntiles, int nNodes)
{
    __shared__ unsigned char lds[LDS_TOTAL];
    // stride-8 pairing kept (m from bit 3); harmless now tables are per-m.
    const int m = (blockIdx.x >> 3) & 1;
    const int bid = (blockIdx.x & 7) | ((blockIdx.x >> 4) << 3);
    const unsigned char* wbase = ws + m * MLP_W_BYTES;
    const unsigned char* rbase = ws + WS_REST_OFF + m * MLP_R_BYTES;
    {
        const uint4* s = (const uint4*)(wbase + W2F);      // w2f|w3f contiguous
        uint4* d = (uint4*)lds;
        for (int i = threadIdx.x; i < 768; i += 256) d[i] = s[i];
        const uint4* sb = (const uint4*)(rbase + 6144);     // b2f|b3f contiguous
        uint4* db = (uint4*)(lds + LB2F);
        for (int i = threadIdx.x; i < 384; i += 256) db[i] = sb[i];
    }

    const int lane = threadIdx.x & 63;
    const int q = lane >> 4, n = lane & 15;
    const int wid = (bid << 2) | (threadIdx.x >> 6);
    const int nwaves = gridDim.x << 1;     // (grid/2 blocks per MLP) * 4 waves
    const float b4s = m ? wb4p[0] : eb4p[0];
    float* __restrict__ outm = out + (m ? nE : 0);
    const _Float16* h1s = h1 + (size_t)(m * 2 + 0) * nNodes * 64;
    const _Float16* h1d = h1 + (size_t)(m * 2 + 1) * nNodes * 64;

    // ---- w4 in registers (8) ----
    float4v w40 = *(const float4v*)(rbase + 0 + lane * 32);
    float4v w41 = *(const float4v*)(rbase + 0 + lane * 32 + 16);

    __syncthreads();

    int2 Gs[4], Gd[4];
    int4 W0 = {0,0,0,0}, W1 = {0,0,0,0}, W2 = {0,0,0,0}, junk = {0,0,0,0};
    int2 I1 = {0,0}, I2 = {0,0}, I3 = {0,0};

    int tile = wid;
    if (tile < ntiles) {
        int t1 = tile + nwaves;     if (t1 >= ntiles) t1 = ntiles - 1;
        int t2 = tile + 2 * nwaves; if (t2 >= ntiles) t2 = ntiles - 1;
        int t3 = tile + 3 * nwaves; if (t3 >= ntiles) t3 = ntiles - 1;
        int2 I0 = load_eidx(eidx, nE, tile, n);
        I1 = load_eidx(eidx, nE, t1, n);
        I2 = load_eidx(eidx, nE, t2, n);
        I3 = load_eidx(eidx, nE, t3, n);
        W0 = warm_h1(h1s, h1d, I0, q);
        W1 = warm_h1(h1s, h1d, I1, q);
        W2 = warm_h1(h1s, h1d, I2, q);
        gather_h1(h1s, h1d, I0, q, Gs, Gd);
    }

#pragma unroll 1
    for (; tile < ntiles; tile += nwaves) {
        // ---- "layer 1": sum + lrelu in packed f16 -> B2 fragments ----
        // t=0 -> B2[0][0..3], t=1 -> B2[1][0..3], t=2 -> B2[0][4..7], t=3 -> B2[1][4..7]
        half8 B2[2];
#pragma unroll
        for (int t = 0; t < 4; ++t) {
            half2v lo = __builtin_bit_cast(half2v, Gs[t].x) + __builtin_bit_cast(half2v, Gd[t].x);
            half2v hi = __builtin_bit_cast(half2v, Gs[t].y) + __builtin_bit_cast(half2v, Gd[t].y);
            half2v sl = lo * (_Float16)0.01f;
            half2v sh = hi * (_Float16)0.01f;
            lo = __builtin_elementwise_max(lo, sl);
            hi = __builtin_elementwise_max(hi, sh);
            int dstv = t & 1, hb = (t >> 1) * 4;
            B2[dstv][hb + 0] = lo[0]; B2[dstv][hb + 1] = lo[1];
            B2[dstv][hb + 2] = hi[0]; B2[dstv][hb + 3] = hi[1];
        }

        // ---- memory-issue block (Gs/Gd dead after sums) ----
        gather_h1(h1s, h1d, I1, q, Gs, Gd);          // tile t+1; warmed 3 iters ago
        junk.x ^= W0.x; junk.y ^= W0.y; junk.z ^= W0.z; junk.w ^= W0.w;
        W0 = W1; W1 = W2;
        W2 = warm_h1(h1s, h1d, I3, q);               // warm tile t+3
        {
            int t4 = tile + 4 * nwaves; if (t4 >= ntiles) t4 = ntiles - 1;
            I1 = I2; I2 = I3;
            I3 = load_eidx(eidx, nE, t4, n);
        }

        // ---- layers 2-4 (A + biases from LDS, w4 regs; high prio) ----
        __builtin_amdgcn_s_setprio(1);
        float4v acc2[4];
#pragma unroll
        for (int t = 0; t < 4; ++t) {
            acc2[t] = *(const float4v*)(lds + LB2F + (t * 64 + lane) * 16);
#pragma unroll
            for (int s = 0; s < 2; ++s) {
                half8 A = *(const half8*)(lds + LW2F + ((t * 2 + s) * 64 + lane) * 16);
                acc2[t] = __builtin_amdgcn_mfma_f32_16x16x32_f16(A, B2[s], acc2[t], 0, 0, 0);
            }
        }
        half8 B3[2];
#pragma unroll
        for (int p = 0; p < 2; ++p) {
            float4v lo4 = acc2[p], hi4 = acc2[p + 2];
            half8 r;
#pragma unroll
            for (int j = 0; j < 4; ++j) {
                float a = lrelu(lo4[j]), b = lrelu(hi4[j]);
                r[j] = (_Float16)a; r[4 + j] = (_Float16)b;
            }
            B3[p] = r;
        }
        float4v acc3[2];
#pragma unroll
        for (int t = 0; t < 2; ++t) {
            acc3[t] = *(const float4v*)(lds + LB3F + (t * 64 + lane) * 16);
#pragma unroll
            for (int s = 0; s < 2; ++s) {
                half8 A = *(const half8*)(lds + LW3F + ((t * 2 + s) * 64 + lane) * 16);
                acc3[t] = __builtin_amdgcn_mfma_f32_16x16x32_f16(A, B3[s], acc3[t], 0, 0, 0);
            }
        }
        float o = 0.f;
#pragma unroll
        for (int r = 0; r < 4; ++r) o = fmaf(lrelu(acc3[0][r]), w40[r], o);
#pragma unroll
        for (int r = 0; r < 4; ++r) o = fmaf(lrelu(acc3[1][r]), w41[r], o);
        o += __shfl_xor(o, 16, 64);
        o += __shfl_xor(o, 32, 64);
        __builtin_amdgcn_s_setprio(0);

        int e = tile * 16 + n;
        if (q == 0 && e < nE)
            outm[e] = o + b4s;
    }

    // consume warm registers (never-taken, data-dependent guard defeats DCE)
    junk.x ^= W0.x ^ W1.x ^ W2.x;
    junk.y ^= W0.y ^ W1.y ^ W2.y;
    junk.z ^= W0.z ^ W1.z ^ W2.z;
    junk.w ^= W0.w ^ W1.w ^ W2.w;
    if (nE < 0 && (junk.x | junk.y | junk.z | junk.w) != 0)
        out[0] = -1.0f;
}

extern "C" void kernel_launch(void* const* d_in, const int* in_sizes, int n_in,
                              void* d_out, int out_size, void* d_ws, size_t ws_size,
                              hipStream_t stream)
{
    const float* x_src = (const float*)d_in[0];
    const float* x_dst = (const float*)d_in[1];
    const int*   eidx  = (const int*)d_in[2];
    const float* ew1 = (const float*)d_in[3];
    const float* eb1 = (const float*)d_in[4];
    const float* ww1 = (const float*)d_in[5];
    const float* wb1 = (const float*)d_in[6];
    const float* ew2 = (const float*)d_in[7];
    const float* eb2 = (const float*)d_in[8];
    const float* ww2 = (const float*)d_in[9];
    const float* wb2 = (const float*)d_in[10];
    const float* ew3 = (const float*)d_in[11];
    const float* eb3 = (const float*)d_in[12];
    const float* ww3 = (const float*)d_in[13];
    const float* wb3 = (const float*)d_in[14];
    const float* ew4 = (const float*)d_in[15];
    const float* eb4 = (const float*)d_in[16];
    const float* ww4 = (const float*)d_in[17];
    const float* wb4 = (const float*)d_in[18];
    float* out = (float*)d_out;

    const int nE = in_sizes[2] / 2;          // 2 x E index array (int32)
    const int nNodes = in_sizes[0] / 64;     // N_NODES
    unsigned char* ws = (unsigned char*)d_ws;
    _Float16* h1 = (_Float16*)(ws + WS_H1_OFF);

    prep_frags<<<68, 256, 0, stream>>>(ew1, eb1, ew2, eb2, ew3, eb3, ew4,
                                       ws, ws + WS_REST_OFF);
    prep_frags<<<68, 256, 0, stream>>>(ww1, wb1, ww2, wb2, ww3, wb3, ww4,
                                       ws + MLP_W_BYTES, ws + WS_REST_OFF + MLP_R_BYTES);
    h1_build<<<(nNodes + 15) / 16, 256, 0, stream>>>(ws, x_src, x_dst, h1, nNodes);

    const int ntiles = (nE + 15) / 16;
    edge_mlp_mfma<<<1024, 256, 0, stream>>>(ws, h1, eidx, eb4, wb4,
                                            out, nE, ntiles, nNodes);
}

// Round 16
// 396.001 us; speedup vs baseline: 2.7482x; 1.0078x over previous
//
#include <hip/hip_runtime.h>

// RegressorHybrid: per-edge 2x MLP (128->64->64->32->1, lrelu 0.01), E=2M, H=64.
// Round 22: XCD-partitioned h1 tables. R21 (per-node layer-1 precompute)
// cut work 57% but FETCH blew up 184->608MB and went latency-bound (MFMA 7%,
// VALU 25%, HBM 2.2TB/s = random-64B ceiling): the h1 tables are PER-MLP
// (25.6MB disjoint) where the old x tables (12.8MB) were SHARED by both
// m-halves - stride-8 pairing deduped nothing, per-XCD L2 working set
// doubled, consume gathers missed where they used to hit, and 12 MFMAs/tile
// can't cover HBM-latency stalls. Fix: partition MLPs ACROSS XCDs
// (blockIdx%8 = XCD round-robin): XCDs 0-3 run m=0, XCDs 4-7 run m=1 ->
// each XCD's L2 sees ONE MLP's 12.8MB = R19's proven footprint (184MB
// FETCH, gathers hit). Mapping is a speed heuristic only (G16-safe).
// Also merged the two prep_frags launches (-1 dispatch ~ -30us overhead).
// Kept from R21: h1_src = x@Wtop + b1, h1_dst = x@Wbot per node (f16,
// 4 tables in ws), per-edge layer 1 = 8 pk_add + lrelu feeding uperm'd
// w2f directly (B2[0]=[t0,t2], B2[1]=[t1,t3]); layers 2-4 A/bias from LDS,
// w4 regs; serial order + in-place gather; warm depth 3 + eidx I1-I3
// prefetch (warm law R1-R5: one warm b128 covers the tile's 64 lines);
// setprio(1) compute / 0 memory; launch_bounds(256,2) (NO occupancy
// request - R7/R8/R20 law: any request near demand spill-chases).
// MFMA layouts: A[m=lane&15][k=(lane>>4)*8+j], B[k=(lane>>4)*8+j][n=lane&15],
//               C/D[row=4*(lane>>4)+reg][col=lane&15].

typedef _Float16 half8  __attribute__((ext_vector_type(8)));
typedef _Float16 half4v __attribute__((ext_vector_type(4)));
typedef _Float16 half2v __attribute__((ext_vector_type(2)));
typedef float    float4v __attribute__((ext_vector_type(4)));

#define MLP_W_BYTES 28672          // w1f 16384 + w2f 8192 + w3f 4096
#define MLP_R_BYTES 12288          // w4f 2048 + b1f 4096 + b2f 4096 + b3f 2048
#define W1F 0
#define W2F 16384
#define W3F 24576
#define LW2F 0                     // LDS: w2f 8192
#define LW3F 8192                  //      w3f 4096
#define LB2F 12288                 //      b2f 4096
#define LB3F 16384                 //      b3f 2048
#define LDS_TOTAL 18432
#define WS_REST_OFF 57344
#define WS_H1_OFF   81920          // 4 tables x nNodes x 128B

__device__ __forceinline__ float lrelu(float x) { return fmaxf(x, 0.01f * x); }

__device__ __forceinline__ int uperm(int k) {
    return 16 * (2 * ((k >> 2) & 1) + ((k >> 5) & 1)) + 4 * ((k >> 3) & 3) + (k & 3);
}

// ---- pack one MLP's weights/biases into per-lane fragment order ----
__device__ __forceinline__ void pack_frags(int idx,
                           const float* __restrict__ w1, const float* __restrict__ b1,
                           const float* __restrict__ w2, const float* __restrict__ b2,
                           const float* __restrict__ w3, const float* __restrict__ b3,
                           const float* __restrict__ w4,
                           unsigned char* __restrict__ dstL,
                           unsigned char* __restrict__ dstR)
{
    if (idx < 8192) {                      // w1f: [16 frags][64 lanes][8 f16]
        int L = (idx >> 3) & 63, j = idx & 7, f = idx >> 9;
        int q = L >> 4, mm = L & 15, t = f >> 2, s = f & 3;
        int k = 32 * s + 8 * q + j;
        ((_Float16*)(dstL + W1F))[idx] = (_Float16)w1[k * 64 + 16 * t + mm];
        return;
    }
    idx -= 8192;
    if (idx < 4096) {                      // w2f: [8][64][8]
        int L = (idx >> 3) & 63, j = idx & 7, f = idx >> 9;
        int q = L >> 4, mm = L & 15, t = f >> 1, s = f & 1;
        int u = uperm(32 * s + 8 * q + j);
        ((_Float16*)(dstL + W2F))[idx] = (_Float16)w2[u * 64 + 16 * t + mm];
        return;
    }
    idx -= 4096;
    if (idx < 2048) {                      // w3f: [4][64][8]
        int L = (idx >> 3) & 63, j = idx & 7, f = idx >> 9;
        int q = L >> 4, mm = L & 15, t = f >> 1, s = f & 1;
        int u = uperm(32 * s + 8 * q + j);
        ((_Float16*)(dstL + W3F))[idx] = (_Float16)w3[u * 32 + 16 * t + mm];
        return;
    }
    idx -= 2048;
    if (idx < 512) {                       // w4f
        int L = idx >> 3, j = idx & 7;
        int q = L >> 4, t = j >> 2, r = j & 3;
        ((float*)(dstR + 0))[idx] = w4[16 * t + 4 * q + r];
        return;
    }
    idx -= 512;
    if (idx < 1024) {                      // b1f
        int t = idx >> 8, L = (idx >> 2) & 63, r = idx & 3, q = L >> 4;
        ((float*)(dstR + 2048))[idx] = b1[16 * t + 4 * q + r];
        return;
    }
    idx -= 1024;
    if (idx < 1024) {                      // b2f
        int t = idx >> 8, L = (idx >> 2) & 63, r = idx & 3, q = L >> 4;
        ((float*)(dstR + 6144))[idx] = b2[16 * t + 4 * q + r];
        return;
    }
    idx -= 1024;
    if (idx < 512) {                       // b3f
        int t = idx >> 8, L = (idx >> 2) & 63, r = idx & 3, q = L >> 4;
        ((float*)(dstR + 10240))[idx] = b3[16 * t + 4 * q + r];
        return;
    }
}

// both MLPs in one launch: blocks [0,68) pack MLP-E, [68,136) pack MLP-W
__global__ void prep_frags2(const float* __restrict__ ew1, const float* __restrict__ eb1,
                            const float* __restrict__ ew2, const float* __restrict__ eb2,
                            const float* __restrict__ ew3, const float* __restrict__ eb3,
                            const float* __restrict__ ew4,
                            const float* __restrict__ ww1, const float* __restrict__ wb1,
                            const float* __restrict__ ww2, const float* __restrict__ wb2,
                            const float* __restrict__ ww3, const float* __restrict__ wb3,
                            const float* __restrict__ ww4,
                            unsigned char* __restrict__ ws)
{
    int m = blockIdx.x >= 68;
    int idx = (blockIdx.x - (m ? 68 : 0)) * blockDim.x + threadIdx.x;
    unsigned char* dstL = ws + m * MLP_W_BYTES;
    unsigned char* dstR = ws + WS_REST_OFF + m * MLP_R_BYTES;
    if (m) pack_frags(idx, ww1, wb1, ww2, wb2, ww3, wb3, ww4, dstL, dstR);
    else   pack_frags(idx, ew1, eb1, ew2, eb2, ew3, eb3, ew4, dstL, dstR);
}

// ---- per-node layer-1 precompute: h1 tables (4 x nNodes x 64 f16) ----
// wave v of each block: m = v>>1 (MLP), side = v&1 (0: src@Wtop+b1, 1: dst@Wbot)
// 16 nodes per block; fp32 x read directly, f16 (RTN) store.
__global__ void h1_build(const unsigned char* __restrict__ ws,
                         const float* __restrict__ xs, const float* __restrict__ xd,
                         _Float16* __restrict__ h1, int nNodes)
{
    const int lane = threadIdx.x & 63;
    const int v = threadIdx.x >> 6;
    const int q = lane >> 4, n = lane & 15;
    const int m = v >> 1, side = v & 1;
    const unsigned char* wbase = ws + m * MLP_W_BYTES;
    const unsigned char* rbase = ws + WS_REST_OFF + m * MLP_R_BYTES;
    int node = blockIdx.x * 16 + n;
    int nc = node < nNodes ? node : nNodes - 1;
    const float* xrow = (side ? xd : xs) + (size_t)nc * 64;

    half8 B[2];
#pragma unroll
    for (int sl = 0; sl < 2; ++sl) {
        float4v lo = *(const float4v*)((const char*)xrow + 128 * sl + 32 * q);
        float4v hi = *(const float4v*)((const char*)xrow + 128 * sl + 32 * q + 16);
        half8 b;
#pragma unroll
        for (int j = 0; j < 4; ++j) { b[j] = (_Float16)lo[j]; b[4 + j] = (_Float16)hi[j]; }
        B[sl] = b;
    }
    float4v acc[4];
#pragma unroll
    for (int t = 0; t < 4; ++t) {
        if (side == 0) acc[t] = *(const float4v*)(rbase + 2048 + (t * 64 + lane) * 16);
        else           acc[t] = (float4v){0.f, 0.f, 0.f, 0.f};
#pragma unroll
        for (int sl = 0; sl < 2; ++sl) {
            int s = 2 * side + sl;
            half8 A = *(const half8*)(wbase + W1F + ((t * 4 + s) * 64 + lane) * 16);
            acc[t] = __builtin_amdgcn_mfma_f32_16x16x32_f16(A, B[sl], acc[t], 0, 0, 0);
        }
    }
    _Float16* orow = h1 + ((size_t)(m * 2 + side) * nNodes + nc) * 64;
#pragma unroll
    for (int t = 0; t < 4; ++t) {
        half4v hv;
#pragma unroll
        for (int r = 0; r < 4; ++r) hv[r] = (_Float16)acc[t][r];     // RTN
        *(half4v*)((char*)orow + 32 * t + 8 * q) = hv;
    }
}

// eidx prefetch: (src,dst) node index pair for this lane's edge of a tile
__device__ __forceinline__ int2 load_eidx(const int* __restrict__ eidx,
                                          int nE, int tile, int n)
{
    int e = tile * 16 + n;
    int ec = e < nE ? e : nE - 1;
    return make_int2(eidx[ec], eidx[nE + ec]);
}

// consume gather: lane (q,n) loads its 4 int2 per side (features 16t+4q+r
// at byte 32t+8q of the 128B h1 row). Hits L1/L2 (warmed earlier).
__device__ __forceinline__ void gather_h1(const _Float16* __restrict__ hs,
                                          const _Float16* __restrict__ hd,
                                          int2 sd, int q, int2* Gs, int2* Gd)
{
    const char* rs = (const char*)(hs + (size_t)sd.x * 64);
    const char* rd = (const char*)(hd + (size_t)sd.y * 64);
#pragma unroll
    for (int t = 0; t < 4; ++t) {
        Gs[t] = *(const int2*)(rs + 32 * t + 8 * q);
        Gd[t] = *(const int2*)(rd + 32 * t + 8 * q);
    }
}

// warm pass: lane (c=q, n) touches line (edge n, combo c) once -> 64
// distinct lines per instruction, one 64B fill each (R1-R5 law).
__device__ __forceinline__ int4 warm_h1(const _Float16* __restrict__ hs,
                                        const _Float16* __restrict__ hd,
                                        int2 sd, int c)
{
    const _Float16* tb = (c & 2) ? hd : hs;
    int idx = (c & 2) ? sd.y : sd.x;
    return *(const int4*)((const char*)(tb + (size_t)idx * 64) + (c & 1) * 64);
}

__global__ __launch_bounds__(256, 2)
void edge_mlp_mfma(const unsigned char* __restrict__ ws,
                   const _Float16* __restrict__ h1,
                   const int* __restrict__ eidx,
                   const float* __restrict__ eb4p, const float* __restrict__ wb4p,
                   float* __restrict__ out, int nE, int ntiles, int nNodes)
{
    __shared__ unsigned char lds[LDS_TOTAL];
    // XCD partition: blockIdx%8 = XCD (round-robin dispatch heuristic).
    // XCDs 0-3 -> m=0, XCDs 4-7 -> m=1: each XCD's L2 sees only ONE MLP's
    // 12.8MB table set = R19's proven per-XCD footprint. Speed-only.
    const int m = (blockIdx.x >> 2) & 1;
    const int bid = (blockIdx.x & 3) | ((blockIdx.x >> 3) << 2);
    const unsigned char* wbase = ws + m * MLP_W_BYTES;
    const unsigned char* rbase = ws + WS_REST_OFF + m * MLP_R_BYTES;
    {
        const uint4* s = (const uint4*)(wbase + W2F);      // w2f|w3f contiguous
        uint4* d = (uint4*)lds;
        for (int i = threadIdx.x; i < 768; i += 256) d[i] = s[i];
        const uint4* sb = (const uint4*)(rbase + 6144);     // b2f|b3f contiguous
        uint4* db = (uint4*)(lds + LB2F);
        for (int i = threadIdx.x; i < 384; i += 256) db[i] = sb[i];
    }

    const int lane = threadIdx.x & 63;
    const int q = lane >> 4, n = lane & 15;
    const int wid = (bid << 2) | (threadIdx.x >> 6);
    const int nwaves = gridDim.x << 1;     // (grid/2 blocks per MLP) * 4 waves
    const float b4s = m ? wb4p[0] : eb4p[0];
    float* __restrict__ outm = out + (m ? nE : 0);
    const _Float16* h1s = h1 + (size_t)(m * 2 + 0) * nNodes * 64;
    const _Float16* h1d = h1 + (size_t)(m * 2 + 1) * nNodes * 64;

    // ---- w4 in registers (8) ----
    float4v w40 = *(const float4v*)(rbase + 0 + lane * 32);
    float4v w41 = *(const float4v*)(rbase + 0 + lane * 32 + 16);

    __syncthreads();

    int2 Gs[4], Gd[4];
    int4 W0 = {0,0,0,0}, W1 = {0,0,0,0}, W2 = {0,0,0,0}, junk = {0,0,0,0};
    int2 I1 = {0,0}, I2 = {0,0}, I3 = {0,0};

    int tile = wid;
    if (tile < ntiles) {
        int t1 = tile + nwaves;     if (t1 >= ntiles) t1 = ntiles - 1;
        int t2 = tile + 2 * nwaves; if (t2 >= ntiles) t2 = ntiles - 1;
        int t3 = tile + 3 * nwaves; if (t3 >= ntiles) t3 = ntiles - 1;
        int2 I0 = load_eidx(eidx, nE, tile, n);
        I1 = load_eidx(eidx, nE, t1, n);
        I2 = load_eidx(eidx, nE, t2, n);
        I3 = load_eidx(eidx, nE, t3, n);
        W0 = warm_h1(h1s, h1d, I0, q);
        W1 = warm_h1(h1s, h1d, I1, q);
        W2 = warm_h1(h1s, h1d, I2, q);
        gather_h1(h1s, h1d, I0, q, Gs, Gd);
    }

#pragma unroll 1
    for (; tile < ntiles; tile += nwaves) {
        // ---- "layer 1": sum + lrelu in packed f16 -> B2 fragments ----
        // t=0 -> B2[0][0..3], t=1 -> B2[1][0..3], t=2 -> B2[0][4..7], t=3 -> B2[1][4..7]
        half8 B2[2];
#pragma unroll
        for (int t = 0; t < 4; ++t) {
            half2v lo = __builtin_bit_cast(half2v, Gs[t].x) + __builtin_bit_cast(half2v, Gd[t].x);
            half2v hi = __builtin_bit_cast(half2v, Gs[t].y) + __builtin_bit_cast(half2v, Gd[t].y);
            half2v sl = lo * (_Float16)0.01f;
            half2v sh = hi * (_Float16)0.01f;
            lo = __builtin_elementwise_max(lo, sl);
            hi = __builtin_elementwise_max(hi, sh);
            int dstv = t & 1, hb = (t >> 1) * 4;
            B2[dstv][hb + 0] = lo[0]; B2[dstv][hb + 1] = lo[1];
            B2[dstv][hb + 2] = hi[0]; B2[dstv][hb + 3] = hi[1];
        }

        // ---- memory-issue block (Gs/Gd dead after sums) ----
        gather_h1(h1s, h1d, I1, q, Gs, Gd);          // tile t+1; warmed 3 iters ago
        junk.x ^= W0.x; junk.y ^= W0.y; junk.z ^= W0.z; junk.w ^= W0.w;
        W0 = W1; W1 = W2;
        W2 = warm_h1(h1s, h1d, I3, q);               // warm tile t+3
        {
            int t4 = tile + 4 * nwaves; if (t4 >= ntiles) t4 = ntiles - 1;
            I1 = I2; I2 = I3;
            I3 = load_eidx(eidx, nE, t4, n);
        }

        // ---- layers 2-4 (A + biases from LDS, w4 regs; high prio) ----
        __builtin_amdgcn_s_setprio(1);
        float4v acc2[4];
#pragma unroll
        for (int t = 0; t < 4; ++t) {
            acc2[t] = *(const float4v*)(lds + LB2F + (t * 64 + lane) * 16);
#pragma unroll
            for (int s = 0; s < 2; ++s) {
                half8 A = *(const half8*)(lds + LW2F + ((t * 2 + s) * 64 + lane) * 16);
                acc2[t] = __builtin_amdgcn_mfma_f32_16x16x32_f16(A, B2[s], acc2[t], 0, 0, 0);
            }
        }
        half8 B3[2];
#pragma unroll
        for (int p = 0; p < 2; ++p) {
            float4v lo4 = acc2[p], hi4 = acc2[p + 2];
            half8 r;
#pragma unroll
            for (int j = 0; j < 4; ++j) {
                float a = lrelu(lo4[j]), b = lrelu(hi4[j]);
                r[j] = (_Float16)a; r[4 + j] = (_Float16)b;
            }
            B3[p] = r;
        }
        float4v acc3[2];
#pragma unroll
        for (int t = 0; t < 2; ++t) {
            acc3[t] = *(const float4v*)(lds + LB3F + (t * 64 + lane) * 16);
#pragma unroll
            for (int s = 0; s < 2; ++s) {
                half8 A = *(const half8*)(lds + LW3F + ((t * 2 + s) * 64 + lane) * 16);
                acc3[t] = __builtin_amdgcn_mfma_f32_16x16x32_f16(A, B3[s], acc3[t], 0, 0, 0);
            }
        }
        float o = 0.f;
#pragma unroll
        for (int r = 0; r < 4; ++r) o = fmaf(lrelu(acc3[0][r]), w40[r], o);
#pragma unroll
        for (int r = 0; r < 4; ++r) o = fmaf(lrelu(acc3[1][r]), w41[r], o);
        o += __shfl_xor(o, 16, 64);
        o += __shfl_xor(o, 32, 64);
        __builtin_amdgcn_s_setprio(0);

        int e = tile * 16 + n;
        if (q == 0 && e < nE)
            outm[e] = o + b4s;
    }

    // consume warm registers (never-taken, data-dependent guard defeats DCE)
    junk.x ^= W0.x ^ W1.x ^ W2.x;
    junk.y ^= W0.y ^ W1.y ^ W2.y;
    junk.z ^= W0.z ^ W1.z ^ W2.z;
    junk.w ^= W0.w ^ W1.w ^ W2.w;
    if (nE < 0 && (junk.x | junk.y | junk.z | junk.w) != 0)
        out[0] = -1.0f;
}

extern "C" void kernel_launch(void* const* d_in, const int* in_sizes, int n_in,
                              void* d_out, int out_size, void* d_ws, size_t ws_size,
                              hipStream_t stream)
{
    const float* x_src = (const float*)d_in[0];
    const float* x_dst = (const float*)d_in[1];
    const int*   eidx  = (const int*)d_in[2];
    const float* ew1 = (const float*)d_in[3];
    const float* eb1 = (const float*)d_in[4];
    const float* ww1 = (const float*)d_in[5];
    const float* wb1 = (const float*)d_in[6];
    const float* ew2 = (const float*)d_in[7];
    const float* eb2 = (const float*)d_in[8];
    const float* ww2 = (const float*)d_in[9];
    const float* wb2 = (const float*)d_in[10];
    const float* ew3 = (const float*)d_in[11];
    const float* eb3 = (const float*)d_in[12];
    const float* ww3 = (const float*)d_in[13];
    const float* wb3 = (const float*)d_in[14];
    const float* ew4 = (const float*)d_in[15];
    const float* eb4 = (const float*)d_in[16];
    const float* ww4 = (const float*)d_in[17];
    const float* wb4 = (const float*)d_in[18];
    float* out = (float*)d_out;

    const int nE = in_sizes[2] / 2;          // 2 x E index array (int32)
    const int nNodes = in_sizes[0] / 64;     // N_NODES
    unsigned char* ws = (unsigned char*)d_ws;
    _Float16* h1 = (_Float16*)(ws + WS_H1_OFF);

    prep_frags2<<<136, 256, 0, stream>>>(ew1, eb1, ew2, eb2, ew3, eb3, ew4,
                                         ww1, wb1, ww2, wb2, ww3, wb3, ww4, ws);
    h1_build<<<(nNodes + 15) / 16, 256, 0, stream>>>(ws, x_src, x_dst, h1, nNodes);

    const int ntiles = (nE + 15) / 16;
    edge_mlp_mfma<<<1024, 256, 0, stream>>>(ws, h1, eidx, eb4, wb4,
                                            out, nE, ntiles, nNodes);
}

// Round 17
// 262.122 us; speedup vs baseline: 4.1518x; 1.5107x over previous
//
#include <hip/hip_runtime.h>

// RegressorHybrid: per-edge 2x MLP (128->64->64->32->1, lrelu 0.01), E=2M, H=64.
// Round 23: restore R19 (best clean: 181us main / 270.7 total) + grid 512.
// R21/R22 (h1 per-node precompute) closed: h1 tables are PER-MLP so gather
// traffic is intrinsically 2x the shared-x scheme (FETCH 482-608MB vs 184MB;
// no pairing/partition can dedup across m) -> latency-bound at 285us. Lesson:
// reduced a non-binding resource (MFMA 27%) while doubling the binding one.
// Also resolved: total-main ~ 89-93us in EVERY round = fixed harness
// overhead (re-poison), not launch count (R22 merge saved ~3us). Metric
// floor = main + ~90.
// Delta vs R19: grid 1024->512. At 2 blocks/CU resident (reg-tier bound),
// 1024 blocks ran as TWO sequential block-rounds: 512 extra prologues (LDS
// stage + warm-pipeline cold start). 512 = exactly resident, one round,
// same total work (61->122 iters/wave). Cannot perturb regalloc.
// R19 structure: skewed pipeline (layer1(t+1) interleaved with layers2-4(t),
// one acc set extra), ALL weights+biases in LDS (38912B; LDS reads proven
// non-binding: R10 -11% at 40->16, R17 null at 16->8), w4 in regs,
// launch_bounds(256,2) with NO occupancy request (R7/R8/R20 law: any
// waves/EU request near demand spill-chases - proven 3x), in-place gather
// (Gcur dead after B1n cast), warm depth 2 + eidx I1-I3 rotating prefetch
// (warm law R1-R5: one warm b128 covers the tile's 64 lines, 1 fill each;
// consume gathers hit L1/L2; FETCH 184MB = raw), setprio(1) compute / 0
// memory, stride-8 pairing (m=(bid>>3)&1) for L2 warm dedup across MLPs.
// MFMA layouts: A[m=lane&15][k=(lane>>4)*8+j], B[k=(lane>>4)*8+j][n=lane&15],
//               C/D[row=4*(lane>>4)+reg][col=lane&15].

typedef _Float16 half8  __attribute__((ext_vector_type(8)));
typedef _Float16 half4v __attribute__((ext_vector_type(4)));
typedef _Float16 half2v __attribute__((ext_vector_type(2)));
typedef float    float4v __attribute__((ext_vector_type(4)));

#define MLP_W_BYTES 28672          // w1f 16384 + w2f 8192 + w3f 4096
#define MLP_R_BYTES 12288          // w4f 2048 + b1f 4096 + b2f 4096 + b3f 2048
#define W1F 0
#define W2F 16384
#define W3F 24576
#define LB1F 28672                 // LDS offsets for biases
#define LB2F 32768
#define LB3F 36864
#define LDS_TOTAL 38912            // w1f+w2f+w3f 28672 + b1f 4096 + b2f 4096 + b3f 2048
#define WS_REST_OFF 57344
#define WS_X16_OFF  81920

__device__ __forceinline__ float lrelu(float x) { return fmaxf(x, 0.01f * x); }

__device__ __forceinline__ int uperm(int k) {
    return 16 * (2 * ((k >> 2) & 1) + ((k >> 5) & 1)) + 4 * ((k >> 3) & 3) + (k & 3);
}

// ---- pack one MLP's weights/biases into per-lane fragment order ----
__global__ void prep_frags(const float* __restrict__ w1, const float* __restrict__ b1,
                           const float* __restrict__ w2, const float* __restrict__ b2,
                           const float* __restrict__ w3, const float* __restrict__ b3,
                           const float* __restrict__ w4,
                           unsigned char* __restrict__ dstL,
                           unsigned char* __restrict__ dstR)
{
    int idx = blockIdx.x * blockDim.x + threadIdx.x;
    if (idx < 8192) {                      // w1f: [16 frags][64 lanes][8 f16]
        int L = (idx >> 3) & 63, j = idx & 7, f = idx >> 9;
        int q = L >> 4, mm = L & 15, t = f >> 2, s = f & 3;
        int k = 32 * s + 8 * q + j;
        ((_Float16*)(dstL + W1F))[idx] = (_Float16)w1[k * 64 + 16 * t + mm];
        return;
    }
    idx -= 8192;
    if (idx < 4096) {                      // w2f: [8][64][8]
        int L = (idx >> 3) & 63, j = idx & 7, f = idx >> 9;
        int q = L >> 4, mm = L & 15, t = f >> 1, s = f & 1;
        int u = uperm(32 * s + 8 * q + j);
        ((_Float16*)(dstL + W2F))[idx] = (_Float16)w2[u * 64 + 16 * t + mm];
        return;
    }
    idx -= 4096;
    if (idx < 2048) {                      // w3f: [4][64][8]
        int L = (idx >> 3) & 63, j = idx & 7, f = idx >> 9;
        int q = L >> 4, mm = L & 15, t = f >> 1, s = f & 1;
        int u = uperm(32 * s + 8 * q + j);
        ((_Float16*)(dstL + W3F))[idx] = (_Float16)w3[u * 32 + 16 * t + mm];
        return;
    }
    idx -= 2048;
    if (idx < 512) {                       // w4f
        int L = idx >> 3, j = idx & 7;
        int q = L >> 4, t = j >> 2, r = j & 3;
        ((float*)(dstR + 0))[idx] = w4[16 * t + 4 * q + r];
        return;
    }
    idx -= 512;
    if (idx < 1024) {                      // b1f
        int t = idx >> 8, L = (idx >> 2) & 63, r = idx & 3, q = L >> 4;
        ((float*)(dstR + 2048))[idx] = b1[16 * t + 4 * q + r];
        return;
    }
    idx -= 1024;
    if (idx < 1024) {                      // b2f
        int t = idx >> 8, L = (idx >> 2) & 63, r = idx & 3, q = L >> 4;
        ((float*)(dstR + 6144))[idx] = b2[16 * t + 4 * q + r];
        return;
    }
    idx -= 1024;
    if (idx < 512) {                       // b3f
        int t = idx >> 8, L = (idx >> 2) & 63, r = idx & 3, q = L >> 4;
        ((float*)(dstR + 10240))[idx] = b3[16 * t + 4 * q + r];
        return;
    }
}

// ---- convert node tables fp32 -> f16 ----
__global__ void prep_nodes(const float* __restrict__ xs, const float* __restrict__ xd,
                           _Float16* __restrict__ os, _Float16* __restrict__ od, int n4)
{
    int stride = gridDim.x * blockDim.x;
    for (int i = blockIdx.x * blockDim.x + threadIdx.x; i < n4; i += stride) {
        float4v a = ((const float4v*)xs)[i];
        float4v b = ((const float4v*)xd)[i];
        half4v ha, hb;
#pragma unroll
        for (int j = 0; j < 4; ++j) { ha[j] = (_Float16)a[j]; hb[j] = (_Float16)b[j]; }
        ((half4v*)os)[i] = ha;
        ((half4v*)od)[i] = hb;
    }
}

// packed repack: cvt_pkrtz (2 f32 -> 2 f16) then lrelu in f16 (pk mul+max).
__device__ __forceinline__ half2v cvt_pk(float a, float b) {
    return __builtin_bit_cast(half2v, __builtin_amdgcn_cvt_pkrtz(a, b));
}

__device__ __forceinline__ half8 repack2(float4v lo, float4v hi) {
    half8 r;
#pragma unroll
    for (int j = 0; j < 2; ++j) {
        half2v a = cvt_pk(lo[2 * j], lo[2 * j + 1]);
        half2v sa = a * (_Float16)0.01f;
        half2v ma = __builtin_elementwise_max(a, sa);
        r[2 * j] = ma[0]; r[2 * j + 1] = ma[1];
        half2v b = cvt_pk(hi[2 * j], hi[2 * j + 1]);
        half2v sb = b * (_Float16)0.01f;
        half2v mb = __builtin_elementwise_max(b, sb);
        r[4 + 2 * j] = mb[0]; r[4 + 2 * j + 1] = mb[1];
    }
    return r;
}

// eidx prefetch: (src,dst) node index pair for this lane's edge of a tile
// (index clamp inside handles all overshoot)
__device__ __forceinline__ int2 load_eidx(const int* __restrict__ eidx,
                                          int nE, int tile, int n)
{
    int e = tile * 16 + n;
    int ec = e < nE ? e : nE - 1;
    return make_int2(eidx[ec], eidx[nE + ec]);
}

// R2-style consume gather from prefetched indices: lane (q,n) loads chunk q
// of edge n's 4 lines. Requests HIT L1/L2 (warmed iterations earlier).
__device__ __forceinline__ void gather_tile(const _Float16* __restrict__ xs,
                                            const _Float16* __restrict__ xd,
                                            int2 sd, int q, int4* G)
{
    const char* rs = (const char*)(xs + (size_t)sd.x * 64);
    const char* rd = (const char*)(xd + (size_t)sd.y * 64);
    G[0] = *(const int4*)(rs + 16 * q);
    G[1] = *(const int4*)(rs + 64 + 16 * q);
    G[2] = *(const int4*)(rd + 16 * q);
    G[3] = *(const int4*)(rd + 64 + 16 * q);
}

// warm pass from prefetched indices: lane (c=q, n) touches line (edge n,
// combo c) once -> 64 distinct lines per instruction, one 64B fill each.
__device__ __forceinline__ int4 warm_tile(const _Float16* __restrict__ xs,
                                          const _Float16* __restrict__ xd,
                                          int2 sd, int c)
{
    int idx = (c & 2) ? sd.y : sd.x;
    const char* base = (const char*)(((c & 2) ? xd : xs) + (size_t)idx * 64);
    return *(const int4*)(base + (c & 1) * 64);
}

__global__ __launch_bounds__(256, 2)
void edge_mlp_mfma(const unsigned char* __restrict__ ws,
                   const _Float16* __restrict__ xs, const _Float16* __restrict__ xd,
                   const int* __restrict__ eidx,
                   const float* __restrict__ eb4p, const float* __restrict__ wb4p,
                   float* __restrict__ out, int nE, int ntiles)
{
    __shared__ unsigned char lds[LDS_TOTAL];
    // stride-8 pairing: blocks 16k+j and 16k+8+j (j<8) run the same tiles for
    // m=0/1 -> same XCD (%8 preserved) and adjacent dispatch -> L2 dedup.
    const int m = (blockIdx.x >> 3) & 1;
    const int bid = (blockIdx.x & 7) | ((blockIdx.x >> 4) << 3);
    const unsigned char* wbase = ws + m * MLP_W_BYTES;
    const unsigned char* rbase = ws + WS_REST_OFF + m * MLP_R_BYTES;
    {
        const uint4* s = (const uint4*)(wbase + W1F);      // w1f|w2f|w3f contiguous
        uint4* d = (uint4*)lds;
        for (int i = threadIdx.x; i < 1792; i += 256) d[i] = s[i];
        const uint4* sb = (const uint4*)(rbase + 2048);     // b1f|b2f|b3f contiguous
        uint4* db = (uint4*)(lds + LB1F);
        for (int i = threadIdx.x; i < 640; i += 256) db[i] = sb[i];
    }

    const int lane = threadIdx.x & 63;
    const int q = lane >> 4, n = lane & 15;
    const int wid = (bid << 2) | (threadIdx.x >> 6);
    const int nwaves = gridDim.x << 1;     // (grid/2 blocks per MLP) * 4 waves
    const float b4s = m ? wb4p[0] : eb4p[0];
    float* __restrict__ outm = out + (m ? nE : 0);

    // ---- only w4 stays in registers (8) ----
    float4v w40 = *(const float4v*)(rbase + 0 + lane * 32);
    float4v w41 = *(const float4v*)(rbase + 0 + lane * 32 + 16);

    __syncthreads();

    int4 Gcur[4];
    int4 W0 = {0,0,0,0}, W1 = {0,0,0,0}, junk = {0,0,0,0};
    int2 I1 = {0,0}, I2 = {0,0}, I3 = {0,0};
    float4v accP[4];

    int tile = wid;
    if (tile < ntiles) {
        int2 I0 = load_eidx(eidx, nE, tile, n);
        I1 = load_eidx(eidx, nE, tile + nwaves, n);
        I2 = load_eidx(eidx, nE, tile + 2 * nwaves, n);
        I3 = load_eidx(eidx, nE, tile + 3 * nwaves, n);
        // warm tiles t, t+1 (folded immediately; gathers queue behind fills)
        int4 ja = warm_tile(xs, xd, I0, q);
        int4 jb = warm_tile(xs, xd, I1, q);
        junk.x ^= ja.x ^ jb.x; junk.y ^= ja.y ^ jb.y;
        junk.z ^= ja.z ^ jb.z; junk.w ^= ja.w ^ jb.w;
        W0 = warm_tile(xs, xd, I2, q);
        W1 = warm_tile(xs, xd, I3, q);
        gather_tile(xs, xd, I0, q, Gcur);

        // ---- skew prologue: layer 1 for the first tile ----
        half8 B1[4];
#pragma unroll
        for (int s = 0; s < 4; ++s) B1[s] = __builtin_bit_cast(half8, Gcur[s]);
#pragma unroll
        for (int t = 0; t < 4; ++t) {
            accP[t] = *(const float4v*)(lds + LB1F + (t * 64 + lane) * 16);
#pragma unroll
            for (int s = 0; s < 4; ++s) {
                half8 A = *(const half8*)(lds + W1F + ((t * 4 + s) * 64 + lane) * 16);
                accP[t] = __builtin_amdgcn_mfma_f32_16x16x32_f16(A, B1[s], accP[t], 0, 0, 0);
            }
        }
        gather_tile(xs, xd, I1, q, Gcur);            // tile+1
        I1 = I2; I2 = I3;
        I3 = load_eidx(eidx, nE, tile + 4 * nwaves, n);
    }

#pragma unroll 1
    for (; tile < ntiles; tile += nwaves) {
        // B-operand for tile t+1 (gathered last iteration into Gcur)
        half8 B1n[4];
#pragma unroll
        for (int s = 0; s < 4; ++s) B1n[s] = __builtin_bit_cast(half8, Gcur[s]);

        __builtin_amdgcn_s_setprio(1);
        // ---- layer 1 of tile t+1 (independent of accP; scheduler fills
        //      layers-2-4 dependency gaps with these 16 MFMAs) ----
        float4v accN[4];
#pragma unroll
        for (int t = 0; t < 4; ++t) {
            accN[t] = *(const float4v*)(lds + LB1F + (t * 64 + lane) * 16);
#pragma unroll
            for (int s = 0; s < 4; ++s) {
                half8 A = *(const half8*)(lds + W1F + ((t * 4 + s) * 64 + lane) * 16);
                accN[t] = __builtin_amdgcn_mfma_f32_16x16x32_f16(A, B1n[s], accN[t], 0, 0, 0);
            }
        }

        // ---- layers 2-4 of tile t (from accP; A-frags from LDS) ----
        half8 B2[2] = { repack2(accP[0], accP[2]), repack2(accP[1], accP[3]) };
        float4v acc2[4];
#pragma unroll
        for (int t = 0; t < 4; ++t) {
            acc2[t] = *(const float4v*)(lds + LB2F + (t * 64 + lane) * 16);
#pragma unroll
            for (int s = 0; s < 2; ++s) {
                half8 A = *(const half8*)(lds + W2F + ((t * 2 + s) * 64 + lane) * 16);
                acc2[t] = __builtin_amdgcn_mfma_f32_16x16x32_f16(A, B2[s], acc2[t], 0, 0, 0);
            }
        }
        half8 B3[2] = { repack2(acc2[0], acc2[2]), repack2(acc2[1], acc2[3]) };
        float4v acc3[2];
#pragma unroll
        for (int t = 0; t < 2; ++t) {
            acc3[t] = *(const float4v*)(lds + LB3F + (t * 64 + lane) * 16);
#pragma unroll
            for (int s = 0; s < 2; ++s) {
                half8 A = *(const half8*)(lds + W3F + ((t * 2 + s) * 64 + lane) * 16);
                acc3[t] = __builtin_amdgcn_mfma_f32_16x16x32_f16(A, B3[s], acc3[t], 0, 0, 0);
            }
        }
        float o = 0.f;
#pragma unroll
        for (int r = 0; r < 4; ++r) o = fmaf(lrelu(acc3[0][r]), w40[r], o);
#pragma unroll
        for (int r = 0; r < 4; ++r) o = fmaf(lrelu(acc3[1][r]), w41[r], o);
        o += __shfl_xor(o, 16, 64);
        o += __shfl_xor(o, 32, 64);
        __builtin_amdgcn_s_setprio(0);

        // ---- memory-issue block (low prio) ----
        // Gcur dead (B1n cast) -> gather tile t+2 in place; lines warmed
        // 2 iterations ago (~15K cyc >> 900cy fill) -> L1/L2 hits.
        gather_tile(xs, xd, I1, q, Gcur);
        // fold warm(t+2) (issued 2 iters ago), shift, issue warm(t+4)
        junk.x ^= W0.x; junk.y ^= W0.y; junk.z ^= W0.z; junk.w ^= W0.w;
        W0 = W1;
        W1 = warm_tile(xs, xd, I3, q);
        // rotate eidx; fetch idx(t+5)
        I1 = I2; I2 = I3;
        I3 = load_eidx(eidx, nE, tile + 5 * nwaves, n);

        int e = tile * 16 + n;
        if (q == 0 && e < nE)
            outm[e] = o + b4s;

#pragma unroll
        for (int t = 0; t < 4; ++t) accP[t] = accN[t];
    }

    // consume warm registers (never-taken, data-dependent guard defeats DCE)
    junk.x ^= W0.x ^ W1.x;
    junk.y ^= W0.y ^ W1.y;
    junk.z ^= W0.z ^ W1.z;
    junk.w ^= W0.w ^ W1.w;
    if (nE < 0 && (junk.x | junk.y | junk.z | junk.w) != 0)
        out[0] = -1.0f;
}

extern "C" void kernel_launch(void* const* d_in, const int* in_sizes, int n_in,
                              void* d_out, int out_size, void* d_ws, size_t ws_size,
                              hipStream_t stream)
{
    const float* x_src = (const float*)d_in[0];
    const float* x_dst = (const float*)d_in[1];
    const int*   eidx  = (const int*)d_in[2];
    const float* ew1 = (const float*)d_in[3];
    const float* eb1 = (const float*)d_in[4];
    const float* ww1 = (const float*)d_in[5];
    const float* wb1 = (const float*)d_in[6];
    const float* ew2 = (const float*)d_in[7];
    const float* eb2 = (const float*)d_in[8];
    const float* ww2 = (const float*)d_in[9];
    const float* wb2 = (const float*)d_in[10];
    const float* ew3 = (const float*)d_in[11];
    const float* eb3 = (const float*)d_in[12];
    const float* ww3 = (const float*)d_in[13];
    const float* wb3 = (const float*)d_in[14];
    const float* ew4 = (const float*)d_in[15];
    const float* eb4 = (const float*)d_in[16];
    const float* ww4 = (const float*)d_in[17];
    const float* wb4 = (const float*)d_in[18];
    float* out = (float*)d_out;

    const int nE = in_sizes[2] / 2;          // 2 x E index array (int32)
    const int nNodeElems = in_sizes[0];      // N_NODES * 64
    unsigned char* ws = (unsigned char*)d_ws;
    _Float16* xs16 = (_Float16*)(ws + WS_X16_OFF);
    _Float16* xd16 = xs16 + nNodeElems;

    prep_frags<<<68, 256, 0, stream>>>(ew1, eb1, ew2, eb2, ew3, eb3, ew4,
                                       ws, ws + WS_REST_OFF);
    prep_frags<<<68, 256, 0, stream>>>(ww1, wb1, ww2, wb2, ww3, wb3, ww4,
                                       ws + MLP_W_BYTES, ws + WS_REST_OFF + MLP_R_BYTES);
    prep_nodes<<<1024, 256, 0, stream>>>(x_src, x_dst, xs16, xd16, nNodeElems / 4);

    const int ntiles = (nE + 15) / 16;
    // grid 512: exactly resident at 2 blocks/CU (reg-tier bound) -> one
    // block-round, no second wave of cold prologues.
    edge_mlp_mfma<<<512, 256, 0, stream>>>(ws, xs16, xd16, eidx, eb4, wb4,
                                           out, nE, ntiles);
}